// Round 1
// baseline (916.893 us; speedup 1.0000x reference)
//
#include <hip/hip_runtime.h>

// Problem constants (fixed by reference): B=4, T=400, U=100, D=512, V=1024
#define Bb 4
#define Tt 400
#define Uu 100
#define Dd 512
#define Vv 1024
#define Mtot (Bb * Tt * Uu)          // 160000 rows, = 1250 * 128 exactly
#define OUT_ELEMS ((size_t)Mtot * Vv) // 163,840,000

typedef unsigned short u16;
typedef unsigned int u32;
typedef short bf16x8 __attribute__((ext_vector_type(8)));
typedef float f32x4 __attribute__((ext_vector_type(4)));
typedef u16 u16x4 __attribute__((ext_vector_type(4)));

// float -> bf16 round-to-nearest-even (inputs finite; no NaN path needed)
__device__ __forceinline__ u16 f2bf(float x) {
    union { float f; u32 u; } v; v.f = x;
    u32 r = v.u + 0x7FFFu + ((v.u >> 16) & 1u);
    return (u16)(r >> 16);
}

// async global->LDS, 16 bytes/lane (dest must be wave-uniform base + lane*16)
__device__ __forceinline__ void async16(const void* g, void* l) {
    __builtin_amdgcn_global_load_lds(
        (const __attribute__((address_space(1))) u32*)g,
        (__attribute__((address_space(3))) u32*)l,
        16, 0, 0);
}

// ---------------- Phase 1: A[m,k] = bf16(tanh(src[b,t,k] + tgt[b,u,k])) ----
// m = b*40000 + t*100 + u; one float4 (4 elems) per thread; exact grid.
__global__ void tanh_fuse(const float* __restrict__ src,
                          const float* __restrict__ tgt,
                          u16* __restrict__ A) {
    int idx = blockIdx.x * 256 + threadIdx.x;   // 0 .. 20,479,999
    int d4 = idx & 127;                          // 512/4 = 128 float4 per row
    int m  = idx >> 7;
    int b  = m / 40000;
    int r  = m - b * 40000;
    int t  = r / 100;
    int u  = r - t * 100;
    const float4 s = ((const float4*)src)[(b * Tt + t) * 128 + d4];
    const float4 g = ((const float4*)tgt)[(b * Uu + u) * 128 + d4];
    u16x4 o;
    o.x = f2bf(tanhf(s.x + g.x));
    o.y = f2bf(tanhf(s.y + g.y));
    o.z = f2bf(tanhf(s.z + g.z));
    o.w = f2bf(tanhf(s.w + g.w));
    ((u16x4*)A)[idx] = o;
}

// ---------------- W fp32 -> bf16, plus length pass-through outputs ---------
__global__ void wconv(const float* __restrict__ W, u16* __restrict__ Wb,
                      const int* __restrict__ slen, const int* __restrict__ tlen,
                      float* __restrict__ out) {
    int idx = blockIdx.x * 256 + threadIdx.x;   // 0 .. 131071 (524288/4)
    float4 w = ((const float4*)W)[idx];
    u16x4 o;
    o.x = f2bf(w.x); o.y = f2bf(w.y); o.z = f2bf(w.z); o.w = f2bf(w.w);
    ((u16x4*)Wb)[idx] = o;
    if (idx < 4)      out[OUT_ELEMS + idx] = (float)slen[idx];
    else if (idx < 8) out[OUT_ELEMS + idx] = (float)tlen[idx - 4];
}

// ---------------- Phase 2: GEMM-BT, 128x128 tile, BK=64, bf16 MFMA ---------
// C[m, v] = sum_k A[m,k] * Wb[v,k] + bias[v].  Exact tiling, no bounds checks.
// Block: 256 threads = 4 waves in 2x2; wave computes 64x64 via 4x4 frags of
// mfma_f32_16x16x32_bf16.  LDS tiles row-major 64-col, no padding
// (global_load_lds requires lane-contiguous dest).
__global__ __launch_bounds__(256) void gemm_mat(const u16* __restrict__ A,
                                                const u16* __restrict__ Wb,
                                                const float* __restrict__ bias,
                                                float* __restrict__ out) {
    __shared__ u16 lA[128 * 64];   // 16 KB
    __shared__ u16 lB[128 * 64];   // 16 KB
    const int tid  = threadIdx.x;
    const int bn   = blockIdx.x & 7;    // 8 N-tiles
    const int bm   = blockIdx.x >> 3;   // 1250 M-tiles
    const int lane = tid & 63;
    const int wave = tid >> 6;
    const int wm   = wave >> 1, wn = wave & 1;
    const int l15  = lane & 15, quad = lane >> 4;

    f32x4 acc[4][4] = {};

    const u16* Ab = A  + (size_t)bm * (128 * 512);
    const u16* Wt = Wb + (size_t)bn * (128 * 512);

    // staging: chunk c = r*256 + tid covers (row = c>>3, kchunk = c&7) of the
    // 128x64 tile; LDS dest = c*16 bytes (contiguous, wave-uniform + lane*16)
    const int srow = tid >> 3;           // row = r*32 + srow
    const int skc  = (tid & 7) * 8;      // k offset within tile (elements)

    const u16* pa = &lA[(wm * 64 + l15) * 64 + quad * 8];
    const u16* pb = &lB[(wn * 64 + l15) * 64 + quad * 8];

    for (int kt = 0; kt < 8; ++kt) {
        const int k0 = kt * 64;
#pragma unroll
        for (int r = 0; r < 4; ++r) {
            const int c   = r * 256 + tid;
            const int row = r * 32 + srow;
            async16(Ab + (size_t)row * 512 + k0 + skc, (void*)&lA[c * 8]);
            async16(Wt + (size_t)row * 512 + k0 + skc, (void*)&lB[c * 8]);
        }
        __syncthreads();   // compiler emits s_waitcnt vmcnt(0) before barrier
#pragma unroll
        for (int kk = 0; kk < 2; ++kk) {
            bf16x8 af[4], bfr[4];
#pragma unroll
            for (int i = 0; i < 4; ++i)
                af[i] = *(const bf16x8*)&pa[i * 1024 + kk * 32];
#pragma unroll
            for (int j = 0; j < 4; ++j)
                bfr[j] = *(const bf16x8*)&pb[j * 1024 + kk * 32];
#pragma unroll
            for (int i = 0; i < 4; ++i)
#pragma unroll
                for (int j = 0; j < 4; ++j)
                    acc[i][j] = __builtin_amdgcn_mfma_f32_16x16x32_bf16(
                        af[i], bfr[j], acc[i][j], 0, 0, 0);
        }
        __syncthreads();
    }

    // epilogue: C/D layout col = lane&15, row = quad*4 + reg
    const int col0  = bn * 128 + wn * 64 + l15;
    const int rbase = bm * 128 + wm * 64 + quad * 4;
    float bv[4];
#pragma unroll
    for (int j = 0; j < 4; ++j) bv[j] = bias[col0 + j * 16];
#pragma unroll
    for (int i = 0; i < 4; ++i) {
#pragma unroll
        for (int r = 0; r < 4; ++r) {
            float* op = out + (size_t)(rbase + i * 16 + r) * 1024 + col0;
#pragma unroll
            for (int j = 0; j < 4; ++j) op[j * 16] = acc[i][j][r] + bv[j];
        }
    }
}

// ---------------- Fallback (ws too small): compute tiles inline ------------
__global__ __launch_bounds__(256) void gemm_inl(const float* __restrict__ src,
                                                const float* __restrict__ tgt,
                                                const float* __restrict__ W,
                                                const float* __restrict__ bias,
                                                float* __restrict__ out) {
    __shared__ u16 lA[128 * 64];
    __shared__ u16 lB[128 * 64];
    const int tid  = threadIdx.x;
    const int bn   = blockIdx.x & 7;
    const int bm   = blockIdx.x >> 3;
    const int lane = tid & 63;
    const int wave = tid >> 6;
    const int wm   = wave >> 1, wn = wave & 1;
    const int l15  = lane & 15, quad = lane >> 4;

    f32x4 acc[4][4] = {};

    const int srow = tid >> 3;
    const int skc  = (tid & 7) * 8;

    const u16* pa = &lA[(wm * 64 + l15) * 64 + quad * 8];
    const u16* pb = &lB[(wn * 64 + l15) * 64 + quad * 8];

    for (int kt = 0; kt < 8; ++kt) {
        const int k0 = kt * 64;
#pragma unroll
        for (int r = 0; r < 4; ++r) {
            const int c   = r * 256 + tid;
            const int row = r * 32 + srow;
            // A tile: tanh(src + tgt) computed inline
            int m = bm * 128 + row;
            int b = m / 40000;
            int rem = m - b * 40000;
            int t = rem / 100;
            int u = rem - t * 100;
            const float* sp = src + (size_t)(b * Tt + t) * 512 + k0 + skc;
            const float* gp = tgt + (size_t)(b * Uu + u) * 512 + k0 + skc;
            float4 s0 = *(const float4*)sp, s1 = *(const float4*)(sp + 4);
            float4 g0 = *(const float4*)gp, g1 = *(const float4*)(gp + 4);
            bf16x8 pk;
            pk[0] = (short)f2bf(tanhf(s0.x + g0.x));
            pk[1] = (short)f2bf(tanhf(s0.y + g0.y));
            pk[2] = (short)f2bf(tanhf(s0.z + g0.z));
            pk[3] = (short)f2bf(tanhf(s0.w + g0.w));
            pk[4] = (short)f2bf(tanhf(s1.x + g1.x));
            pk[5] = (short)f2bf(tanhf(s1.y + g1.y));
            pk[6] = (short)f2bf(tanhf(s1.z + g1.z));
            pk[7] = (short)f2bf(tanhf(s1.w + g1.w));
            *(bf16x8*)&lA[c * 8] = pk;
            // W tile: fp32 -> bf16 inline
            const float* wp = W + (size_t)(bn * 128 + row) * 512 + k0 + skc;
            float4 w0 = *(const float4*)wp, w1 = *(const float4*)(wp + 4);
            bf16x8 wk;
            wk[0] = (short)f2bf(w0.x); wk[1] = (short)f2bf(w0.y);
            wk[2] = (short)f2bf(w0.z); wk[3] = (short)f2bf(w0.w);
            wk[4] = (short)f2bf(w1.x); wk[5] = (short)f2bf(w1.y);
            wk[6] = (short)f2bf(w1.z); wk[7] = (short)f2bf(w1.w);
            *(bf16x8*)&lB[c * 8] = wk;
        }
        __syncthreads();
#pragma unroll
        for (int kk = 0; kk < 2; ++kk) {
            bf16x8 af[4], bfr[4];
#pragma unroll
            for (int i = 0; i < 4; ++i)
                af[i] = *(const bf16x8*)&pa[i * 1024 + kk * 32];
#pragma unroll
            for (int j = 0; j < 4; ++j)
                bfr[j] = *(const bf16x8*)&pb[j * 1024 + kk * 32];
#pragma unroll
            for (int i = 0; i < 4; ++i)
#pragma unroll
                for (int j = 0; j < 4; ++j)
                    acc[i][j] = __builtin_amdgcn_mfma_f32_16x16x32_bf16(
                        af[i], bfr[j], acc[i][j], 0, 0, 0);
        }
        __syncthreads();
    }

    const int col0  = bn * 128 + wn * 64 + l15;
    const int rbase = bm * 128 + wm * 64 + quad * 4;
    float bv[4];
#pragma unroll
    for (int j = 0; j < 4; ++j) bv[j] = bias[col0 + j * 16];
#pragma unroll
    for (int i = 0; i < 4; ++i) {
#pragma unroll
        for (int r = 0; r < 4; ++r) {
            float* op = out + (size_t)(rbase + i * 16 + r) * 1024 + col0;
#pragma unroll
            for (int j = 0; j < 4; ++j) op[j * 16] = acc[i][j][r] + bv[j];
        }
    }
}

__global__ void lenout(const int* __restrict__ slen, const int* __restrict__ tlen,
                       float* __restrict__ out) {
    int i = threadIdx.x;
    if (i < 4)      out[OUT_ELEMS + i] = (float)slen[i];
    else if (i < 8) out[OUT_ELEMS + i] = (float)tlen[i - 4];
}

extern "C" void kernel_launch(void* const* d_in, const int* in_sizes, int n_in,
                              void* d_out, int out_size, void* d_ws, size_t ws_size,
                              hipStream_t stream) {
    const float* src  = (const float*)d_in[0];
    const int*   slen = (const int*)d_in[1];
    const float* tgt  = (const float*)d_in[2];
    const int*   tlen = (const int*)d_in[3];
    const float* W    = (const float*)d_in[4];
    const float* bias = (const float*)d_in[5];
    float* out = (float*)d_out;

    const size_t needA = (size_t)Mtot * Dd * 2;  // 163,840,000 B
    const size_t needW = (size_t)Vv * Dd * 2;    //   1,048,576 B

    if (d_ws != nullptr && ws_size >= needA + needW) {
        u16* Abf = (u16*)d_ws;
        u16* Wbf = (u16*)((char*)d_ws + needA);
        tanh_fuse<<<dim3(80000), dim3(256), 0, stream>>>(src, tgt, Abf);
        wconv<<<dim3(512), dim3(256), 0, stream>>>(W, Wbf, slen, tlen, out);
        gemm_mat<<<dim3(10000), dim3(256), 0, stream>>>(Abf, Wbf, bias, out);
    } else {
        lenout<<<dim3(1), dim3(64), 0, stream>>>(slen, tlen, out);
        gemm_inl<<<dim3(10000), dim3(256), 0, stream>>>(src, tgt, W, bias, out);
    }
}